// Round 4
// baseline (623.041 us; speedup 1.0000x reference)
//
#include <hip/hip_runtime.h>

// Problem dims (fixed)
#define BB 2
#define LL 1024
#define DD 1024
#define HH 16
#define HD 64
#define DFFN 4096
#define MM (BB*LL)   // 2048 rows
#define QS 3072      // fused QKV row stride

using u16 = unsigned short;
typedef __bf16 bf16x8 __attribute__((ext_vector_type(8)));
typedef float f32x4 __attribute__((ext_vector_type(4)));

__device__ __forceinline__ float b2f(u16 u) {
  union { unsigned int i; float f; } v; v.i = ((unsigned int)u) << 16; return v.f;
}
__device__ __forceinline__ u16 f2b(float f) {
  union { float f; unsigned int i; } v; v.f = f;
  unsigned int x = v.i;
  return (u16)((x + 0x7fffu + ((x >> 16) & 1u)) >> 16);  // RNE, finite values
}
__device__ __forceinline__ float gelu_exact(float x) {
  return 0.5f * x * (1.0f + erff(x * 0.70710678118654752f));
}
__device__ __forceinline__ void gl2lds16(const void* g, void* l) {
  __builtin_amdgcn_global_load_lds((const __attribute__((address_space(1))) void*)g,
                                   (__attribute__((address_space(3))) void*)l, 16, 0, 0);
}

// counted waitcnt (T4): keep prefetch in flight across barriers; never drain to 0 mid-loop
template<int N>
__device__ __forceinline__ void s_wait_vm() {
  if constexpr (N == 0)       asm volatile("s_waitcnt vmcnt(0) lgkmcnt(0)" ::: "memory");
  else if constexpr (N == 3)  asm volatile("s_waitcnt vmcnt(3) lgkmcnt(0)" ::: "memory");
  else if constexpr (N == 4)  asm volatile("s_waitcnt vmcnt(4) lgkmcnt(0)" ::: "memory");
  else if constexpr (N == 6)  asm volatile("s_waitcnt vmcnt(6) lgkmcnt(0)" ::: "memory");
  else if constexpr (N == 8)  asm volatile("s_waitcnt vmcnt(8) lgkmcnt(0)" ::: "memory");
  else if constexpr (N == 12) asm volatile("s_waitcnt vmcnt(12) lgkmcnt(0)" ::: "memory");
  __builtin_amdgcn_sched_barrier(0);
}

// T1: chunked XCD swizzle. HW assigns physical block b to XCD b%8 (round-robin).
// Remap so each group of 16 consecutive LOGICAL blocks (sharing an A-panel) lands
// on one XCD. Bijective when nb % 128 == 0 (grids that don't qualify -> identity).
__device__ __forceinline__ void xcd_remap(int& bx, int& by, int& bz) {
  const int gx = gridDim.x, gy = gridDim.y;
  const int nb = gx * gy * gridDim.z;
  int b = blockIdx.x + gx * (blockIdx.y + gy * blockIdx.z);
  if ((nb & 127) == 0) {
    const int xcd = b & 7, seq = b >> 3;
    b = (((seq >> 4) << 3) + xcd) * 16 + (seq & 15);
  }
  bx = b % gx; const int rest = b / gx;
  by = rest % gy; bz = rest / gy;
}

// ---------------- weight casts fp32 -> bf16 ----------------
__global__ __launch_bounds__(256) void castw_kernel(const float* __restrict__ in,
                                                    u16* __restrict__ out, int n8) {
  int i = blockIdx.x * 256 + threadIdx.x;
  if (i >= n8) return;
  const float4 a = reinterpret_cast<const float4*>(in)[2 * i];
  const float4 b = reinterpret_cast<const float4*>(in)[2 * i + 1];
  uint4 o;
  o.x = (unsigned)f2b(a.x) | ((unsigned)f2b(a.y) << 16);
  o.y = (unsigned)f2b(a.z) | ((unsigned)f2b(a.w) << 16);
  o.z = (unsigned)f2b(b.x) | ((unsigned)f2b(b.y) << 16);
  o.w = (unsigned)f2b(b.z) | ((unsigned)f2b(b.w) << 16);
  reinterpret_cast<uint4*>(out)[i] = o;
}
__global__ __launch_bounds__(256) void castw3_kernel(const float* __restrict__ s0,
                                                     const float* __restrict__ s1,
                                                     const float* __restrict__ s2,
                                                     u16* __restrict__ out, int n8) {
  int i = blockIdx.x * 256 + threadIdx.x;
  if (i >= n8) return;
  const float* in = (blockIdx.y == 0) ? s0 : (blockIdx.y == 1) ? s1 : s2;
  u16* dst = out + (size_t)blockIdx.y * n8 * 8;
  const float4 a = reinterpret_cast<const float4*>(in)[2 * i];
  const float4 b = reinterpret_cast<const float4*>(in)[2 * i + 1];
  uint4 o;
  o.x = (unsigned)f2b(a.x) | ((unsigned)f2b(a.y) << 16);
  o.y = (unsigned)f2b(a.z) | ((unsigned)f2b(a.w) << 16);
  o.z = (unsigned)f2b(b.x) | ((unsigned)f2b(b.y) << 16);
  o.w = (unsigned)f2b(b.z) | ((unsigned)f2b(b.w) << 16);
  reinterpret_cast<uint4*>(dst)[i] = o;
}

// ---------------- out = resid (+ bias), fp32 ----------------
__global__ __launch_bounds__(256) void init_out_kernel(float* __restrict__ out,
                                                       const float* __restrict__ resid,
                                                       const float* __restrict__ bias) {
  const int i = blockIdx.x * 256 + threadIdx.x;   // float4 index
  float4 v = reinterpret_cast<const float4*>(resid)[i];
  if (bias != nullptr) {
    const float4 bv = *reinterpret_cast<const float4*>(bias + ((i * 4) & (DD - 1)));
    v.x += bv.x; v.y += bv.y; v.z += bv.z; v.w += bv.w;
  }
  reinterpret_cast<float4*>(out)[i] = v;
}

// ---------------- rmsnorm (fp32 in, fp32 weight, bf16 out) ----------------
__global__ __launch_bounds__(256) void rmsnorm_kernel(const float* __restrict__ x,
                                                      const float* __restrict__ w,
                                                      u16* __restrict__ out) {
  const int row = blockIdx.x, t = threadIdx.x;
  const float4 v = reinterpret_cast<const float4*>(x + (size_t)row * DD)[t];
  float ss = v.x*v.x + v.y*v.y + v.z*v.z + v.w*v.w;
  #pragma unroll
  for (int o = 32; o > 0; o >>= 1) ss += __shfl_down(ss, o);
  __shared__ float red[4];
  if ((t & 63) == 0) red[t >> 6] = ss;
  __syncthreads();
  const float inv = rsqrtf((red[0] + red[1] + red[2] + red[3]) * (1.0f / DD) + 1e-5f);
  const float4 wv = reinterpret_cast<const float4*>(w)[t];
  ushort4 o;
  o.x = f2b(v.x * inv * wv.x);
  o.y = f2b(v.y * inv * wv.y);
  o.z = f2b(v.z * inv * wv.z);
  o.w = f2b(v.w * inv * wv.w);
  reinterpret_cast<ushort4*>(out + (size_t)row * DD)[t] = o;
}

// ---- BK=32 staging with bank-conflict-free chunk permutation ----
// 16B chunk of logical (row r, kchunk q) lives at LDS slot
//   p = (r&7) | (q<<3) | ((r>>3)<<5)
// Read bank = 4*(r&7) -> 16 lanes spread over 8 banks = 2-way (free).
// dma inverts the permutation on the GLOBAL address (slot c -> row=(c&7)|((c>>5)<<3),
// q=(c>>3)&3); each wave still covers 16 full 64B lines -> coalescing preserved.
template<int ROWS, int NT>
__device__ __forceinline__ void dma32(const u16* __restrict__ g, int r0, int K, int kt,
                                      int t, u16* lds) {
  #pragma unroll
  for (int i = 0; i < ROWS * 4 / NT; i++) {
    const int c = i * NT + t;
    const int row = (c & 7) | ((c >> 5) << 3);
    const int kc = (c >> 3) & 3;
    gl2lds16(g + (size_t)(r0 + row) * K + kt + kc * 8, &lds[c * 8]);
  }
}
__device__ __forceinline__ const bf16x8* lds_frag(const u16* base, int r, int fq) {
  const int p = (r & 7) | (fq << 3) | ((r >> 3) << 5);
  return reinterpret_cast<const bf16x8*>(&base[p * 8]);
}
__device__ __forceinline__ void mfma_tile32(const u16* Asb, const u16* Bsb,
                                            int wm, int wn, int fr, int fq, f32x4 acc[4][4]) {
  bf16x8 af[4], bfv[4];
  #pragma unroll
  for (int i = 0; i < 4; i++) af[i] = *lds_frag(Asb, wm + i * 16 + fr, fq);
  #pragma unroll
  for (int j = 0; j < 4; j++) bfv[j] = *lds_frag(Bsb, wn + j * 16 + fr, fq);
  #pragma unroll
  for (int i = 0; i < 4; i++)
    #pragma unroll
    for (int j = 0; j < 4; j++)
      acc[i][j] = __builtin_amdgcn_mfma_f32_16x16x32_bf16(af[i], bfv[j], acc[i][j], 0, 0, 0);
}

// ---- T3+T4 deep pipeline: 4 LDS buffers, stage t+3 in flight, counted vmcnt ----
// Per step: wait vmcnt(2L) lgkm(0) [stage(t) landed, prev reads retired];
// s_barrier; issue stage(t+3); compute buf[t%4].
// WAR safety: buf[(t+3)%4] == buf[(t-1)%4]; its reads were retired by every
// wave's lgkmcnt(0) before this barrier.
template<int BM, int BN>
__device__ __forceinline__ void gemm_pipeline(const u16* __restrict__ A,
                                              const u16* __restrict__ Wb,
                                              int K, int k0, int nt, int m0, int n0,
                                              u16* As, u16* Bs, int t,
                                              int wm, int wn, int fr, int fq,
                                              f32x4 acc[4][4]) {
  constexpr int NT = (BM / 64) * (BN / 64) * 64;
  constexpr int L = (BM + BN) * 4 / NT;   // loads/thread/stage
  // prologue: stage tiles 0..2 (nt >= 3 always in our shapes)
  #pragma unroll
  for (int s = 0; s < 3; ++s) {
    dma32<BM, NT>(A, m0, K, k0 + s * 32, t, As + s * BM * 32);
    dma32<BN, NT>(Wb, n0, K, k0 + s * 32, t, Bs + s * BN * 32);
  }
  int pb = 0;
  for (int tt = 0; tt < nt; ++tt) {
    const int ahead = nt - 1 - tt;       // wave-uniform
    if (ahead >= 2)      s_wait_vm<2 * L>();
    else if (ahead == 1) s_wait_vm<L>();
    else                 s_wait_vm<0>();
    __builtin_amdgcn_s_barrier();
    __builtin_amdgcn_sched_barrier(0);
    if (tt + 3 < nt) {
      int p3 = pb + 3; if (p3 >= 4) p3 -= 4;
      dma32<BM, NT>(A, m0, K, k0 + (tt + 3) * 32, t, As + p3 * BM * 32);
      dma32<BN, NT>(Wb, n0, K, k0 + (tt + 3) * 32, t, Bs + p3 * BN * 32);
      __builtin_amdgcn_sched_barrier(0);
    }
    mfma_tile32(As + pb * BM * 32, Bs + pb * BN * 32, wm, wn, fr, fq, acc);
    pb = (pb + 1) & 3;
  }
}

// ---------------- MFMA GEMM: C[M,N](bf16) = A(bf16) @ Wb(bf16,[N,K])^T ----------------
// 256x128 tile, 8 waves (512 thr): 85 FLOP per staged byte (2x the 128x64 tile).
template<int BM, int BN, int ACT>
__global__ __launch_bounds__((BM/64)*(BN/64)*64)
void mfma_gemm(const u16* __restrict__ A, const u16* __restrict__ Wb,
               u16* __restrict__ Cb, int N, int K) {
  constexpr int WCOLS = BN / 64;
  __shared__ u16 As[4 * BM * 32];
  __shared__ u16 Bs[4 * BN * 32];
  int bx, by, bz;
  xcd_remap(bx, by, bz);
  const int t = threadIdx.x;
  const int lane = t & 63, w = t >> 6;
  const int wm = (w / WCOLS) * 64, wn = (w % WCOLS) * 64;
  const int m0 = by * BM, n0 = bx * BN;
  const int fr = lane & 15, fq = lane >> 4;

  f32x4 acc[4][4] = {};
  gemm_pipeline<BM, BN>(A, Wb, K, 0, K / 32, m0, n0, As, Bs, t, wm, wn, fr, fq, acc);

  #pragma unroll
  for (int i = 0; i < 4; i++)
    #pragma unroll
    for (int j = 0; j < 4; j++)
      #pragma unroll
      for (int r = 0; r < 4; r++) {
        const int row = m0 + wm + i * 16 + fq * 4 + r;
        const int col = n0 + wn + j * 16 + fr;
        float val = acc[i][j][r];
        if (ACT == 1) val = gelu_exact(val);
        Cb[(size_t)row * N + col] = f2b(val);
      }
}

// ---------------- split-K MFMA GEMM: Co(f32) += A @ Wb^T  (Co pre-initialized) ----------------
template<int BM, int BN, int SPLIT>
__global__ __launch_bounds__((BM/64)*(BN/64)*64)
void mfma_gemm_sk(const u16* __restrict__ A, const u16* __restrict__ Wb,
                  float* __restrict__ Co, int N, int K) {
  constexpr int WCOLS = BN / 64;
  __shared__ u16 As[4 * BM * 32];
  __shared__ u16 Bs[4 * BN * 32];
  int bx, by, bz;
  xcd_remap(bx, by, bz);
  const int t = threadIdx.x;
  const int lane = t & 63, w = t >> 6;
  const int wm = (w / WCOLS) * 64, wn = (w % WCOLS) * 64;
  const int m0 = by * BM, n0 = bx * BN;
  const int fr = lane & 15, fq = lane >> 4;
  const int Kc = K / SPLIT, k0 = bz * Kc;

  f32x4 acc[4][4] = {};
  gemm_pipeline<BM, BN>(A, Wb, K, k0, Kc / 32, m0, n0, As, Bs, t, wm, wn, fr, fq, acc);

  #pragma unroll
  for (int i = 0; i < 4; i++)
    #pragma unroll
    for (int j = 0; j < 4; j++)
      #pragma unroll
      for (int r = 0; r < 4; r++) {
        const int row = m0 + wm + i * 16 + fq * 4 + r;
        const int col = n0 + wn + j * 16 + fr;
        unsafeAtomicAdd(&Co[(size_t)row * N + col], acc[i][j][r]);
      }
}

// ---------------- K/V transpose via LDS, coalesced both sides ----------------
__global__ __launch_bounds__(256) void kv_trans(const u16* __restrict__ QKV,
                                                u16* __restrict__ Kt, u16* __restrict__ Vt) {
  __shared__ u16 T[64][72];
  const int tile = blockIdx.x;
  const int h2 = blockIdx.y;             // h = h2&15, which = h2>>4 (0=K, 1=V)
  const int b = blockIdx.z;
  const int h = h2 & 15, which = h2 >> 4;
  const int t = threadIdx.x;
  const int pos = t >> 2, d0 = (t & 3) * 16;
  const u16* src = QKV + ((size_t)(b * LL) + tile * 64 + pos) * QS + 1024 + which * 1024 + h * HD + d0;
  union { uint4 u[2]; u16 s[16]; } pk;
  pk.u[0] = reinterpret_cast<const uint4*>(src)[0];
  pk.u[1] = reinterpret_cast<const uint4*>(src)[1];
  #pragma unroll
  for (int j = 0; j < 16; j++) T[d0 + j][pos] = pk.s[j];
  __syncthreads();
  const int d = t >> 2, p0 = (t & 3) * 16;
  u16* dst = (which ? Vt : Kt) + ((size_t)(b * HH + h) * HD + d) * LL + tile * 64 + p0;
  union { uint4 u[2]; u16 s[16]; } ok;
  #pragma unroll
  for (int j = 0; j < 16; j++) ok.s[j] = T[d][p0 + j];
  reinterpret_cast<uint4*>(dst)[0] = ok.u[0];
  reinterpret_cast<uint4*>(dst)[1] = ok.u[1];
}

// ---------------- attention phase 1 ----------------
__global__ __launch_bounds__(256) void attn_phase1(const u16* __restrict__ QKV,
                                                   const u16* __restrict__ Kt,
                                                   const u16* __restrict__ Vt,
                                                   u16* __restrict__ Oa,
                                                   u16* __restrict__ Slt) {
  __shared__ u16 Ss[4][16][64];
  const int tile = blockIdx.x, h = blockIdx.y, b = blockIdx.z;
  const int t = threadIdx.x, lane = t & 63, w = t >> 6;
  const int fr = lane & 15, fq = lane >> 4;
  const size_t tok0 = (size_t)(b * LL + tile * 64);
  const size_t bh = (size_t)(b * HH + h);
  const u16* Qb  = QKV + tok0 * QS + h * HD;
  const u16* Kb  = Qb + 1024;
  const u16* Ktb = Kt + bh * (HD * LL) + tile * 64;
  const u16* Vtb = Vt + bh * (HD * LL) + tile * 64;

  // ---- S = Q K^T ----
  bf16x8 aq[2], bk[4][2];
  #pragma unroll
  for (int kh = 0; kh < 2; kh++)
    aq[kh] = *reinterpret_cast<const bf16x8*>(Qb + (size_t)(16*w + fr) * QS + kh*32 + fq*8);
  #pragma unroll
  for (int n4 = 0; n4 < 4; n4++)
    #pragma unroll
    for (int kh = 0; kh < 2; kh++)
      bk[n4][kh] = *reinterpret_cast<const bf16x8*>(Kb + (size_t)(16*n4 + fr) * QS + kh*32 + fq*8);
  f32x4 sacc[4] = {};
  #pragma unroll
  for (int n4 = 0; n4 < 4; n4++) {
    sacc[n4] = __builtin_amdgcn_mfma_f32_16x16x32_bf16(aq[0], bk[n4][0], sacc[n4], 0, 0, 0);
    sacc[n4] = __builtin_amdgcn_mfma_f32_16x16x32_bf16(aq[1], bk[n4][1], sacc[n4], 0, 0, 0);
  }
  #pragma unroll
  for (int n4 = 0; n4 < 4; n4++)
    #pragma unroll
    for (int r = 0; r < 4; r++) {
      const bool keep = (16*w + 4*fq + r) >= (16*n4 + fr);
      Ss[w][4*fq + r][16*n4 + fr] = keep ? f2b(sacc[n4][r]) : (u16)0;
    }
  __syncthreads();

  // ---- Slt = V^T K ----
  bf16x8 va[2], kt[4][2];
  #pragma unroll
  for (int kh = 0; kh < 2; kh++)
    va[kh] = *reinterpret_cast<const bf16x8*>(Vtb + (size_t)(16*w + fr) * LL + kh*32 + fq*8);
  #pragma unroll
  for (int n4 = 0; n4 < 4; n4++)
    #pragma unroll
    for (int kh = 0; kh < 2; kh++)
      kt[n4][kh] = *reinterpret_cast<const bf16x8*>(Ktb + (size_t)(16*n4 + fr) * LL + kh*32 + fq*8);
  f32x4 lacc[4] = {};
  #pragma unroll
  for (int n4 = 0; n4 < 4; n4++) {
    lacc[n4] = __builtin_amdgcn_mfma_f32_16x16x32_bf16(va[0], kt[n4][0], lacc[n4], 0, 0, 0);
    lacc[n4] = __builtin_amdgcn_mfma_f32_16x16x32_bf16(va[1], kt[n4][1], lacc[n4], 0, 0, 0);
  }
  u16* So = Slt + (bh * 16 + tile) * 4096;
  #pragma unroll
  for (int n4 = 0; n4 < 4; n4++)
    #pragma unroll
    for (int r = 0; r < 4; r++)
      So[(size_t)(16*w + 4*fq + r) * 64 + 16*n4 + fr] = f2b(lacc[n4][r]);

  // ---- O_intra = S V ----
  bf16x8 sa[2], vb[4][2];
  #pragma unroll
  for (int kh = 0; kh < 2; kh++)
    sa[kh] = *reinterpret_cast<const bf16x8*>(&Ss[w][fr][kh*32 + fq*8]);
  #pragma unroll
  for (int n4 = 0; n4 < 4; n4++)
    #pragma unroll
    for (int kh = 0; kh < 2; kh++)
      vb[n4][kh] = *reinterpret_cast<const bf16x8*>(Vtb + (size_t)(16*n4 + fr) * LL + kh*32 + fq*8);
  f32x4 oacc[4] = {};
  #pragma unroll
  for (int n4 = 0; n4 < 4; n4++) {
    oacc[n4] = __builtin_amdgcn_mfma_f32_16x16x32_bf16(sa[0], vb[n4][0], oacc[n4], 0, 0, 0);
    oacc[n4] = __builtin_amdgcn_mfma_f32_16x16x32_bf16(sa[1], vb[n4][1], oacc[n4], 0, 0, 0);
  }
  u16* Ob = Oa + (tok0 + 16*w) * DD + h * HD;
  #pragma unroll
  for (int n4 = 0; n4 < 4; n4++)
    #pragma unroll
    for (int r = 0; r < 4; r++)
      Ob[(size_t)(4*fq + r) * DD + 16*n4 + fr] = f2b(oacc[n4][r]);
}

// ---------------- attention phase 2: exclusive fp32 scan ----------------
__global__ __launch_bounds__(256) void attn_phase2(const u16* __restrict__ Slt,
                                                   u16* __restrict__ Wc) {
  const int rg = blockIdx.x, h = blockIdx.y, b = blockIdx.z;
  const size_t base = ((size_t)((b * HH + h) * 16)) * 4096 + rg * 512 + threadIdx.x * 2;
  float r0 = 0.f, r1 = 0.f;
  for (int tl = 0; tl < 16; tl++) {
    const size_t p = base + (size_t)tl * 4096;
    const unsigned d = *reinterpret_cast<const unsigned*>(Slt + p);
    *reinterpret_cast<unsigned*>(Wc + p) = (unsigned)f2b(r0) | ((unsigned)f2b(r1) << 16);
    r0 += b2f((u16)(d & 0xffff));
    r1 += b2f((u16)(d >> 16));
  }
}

// ---------------- attention phase 3: O += Q @ W_prev ----------------
__global__ __launch_bounds__(256) void attn_phase3(const u16* __restrict__ QKV,
                                                   const u16* __restrict__ Wc,
                                                   u16* __restrict__ Oa) {
  const int tile = blockIdx.x, h = blockIdx.y, b = blockIdx.z;
  const int t = threadIdx.x, lane = t & 63, w = t >> 6;
  const int fr = lane & 15, fq = lane >> 4;
  const size_t tok0 = (size_t)(b * LL + tile * 64);
  const size_t bh = (size_t)(b * HH + h);
  const u16* Qb = QKV + tok0 * QS + h * HD;
  const u16* Wb = Wc + (bh * 16 + tile) * 4096;

  bf16x8 aq[2], wb[4][2];
  #pragma unroll
  for (int kh = 0; kh < 2; kh++)
    aq[kh] = *reinterpret_cast<const bf16x8*>(Qb + (size_t)(16*w + fr) * QS + kh*32 + fq*8);
  #pragma unroll
  for (int n4 = 0; n4 < 4; n4++)
    #pragma unroll
    for (int kh = 0; kh < 2; kh++)
      wb[n4][kh] = *reinterpret_cast<const bf16x8*>(Wb + (size_t)(16*n4 + fr) * 64 + kh*32 + fq*8);
  f32x4 oacc[4] = {};
  #pragma unroll
  for (int n4 = 0; n4 < 4; n4++) {
    oacc[n4] = __builtin_amdgcn_mfma_f32_16x16x32_bf16(aq[0], wb[n4][0], oacc[n4], 0, 0, 0);
    oacc[n4] = __builtin_amdgcn_mfma_f32_16x16x32_bf16(aq[1], wb[n4][1], oacc[n4], 0, 0, 0);
  }
  u16* Ob = Oa + (tok0 + 16*w) * DD + h * HD;
  #pragma unroll
  for (int n4 = 0; n4 < 4; n4++)
    #pragma unroll
    for (int r = 0; r < 4; r++) {
      const size_t idx = (size_t)(4*fq + r) * DD + 16*n4 + fr;
      Ob[idx] = f2b(b2f(Ob[idx]) + oacc[n4][r]);
    }
}

// ---------------- host ----------------
// ws map (32 MB): wbuf 0..8 (time-shared with Slt 0..4 / Wcum 4..8 during attn)
// h/a/m 8..12 | qkv 12..24 | f 12..28 (qkv/Vt dead) | Vt 24..28 | Kt 28..32
// fp32 residual stream lives in d_out.
extern "C" void kernel_launch(void* const* d_in, const int* in_sizes, int n_in,
                              void* d_out, int out_size, void* d_ws, size_t ws_size,
                              hipStream_t stream) {
  const float* x_in = (const float*)d_in[0];
  const float* qw   = (const float*)d_in[1];
  const float* kw   = (const float*)d_in[2];
  const float* vw   = (const float*)d_in[3];
  const float* ow   = (const float*)d_in[4];
  const float* pn   = (const float*)d_in[5];
  const float* ln   = (const float*)d_in[6];
  const float* fcw  = (const float*)d_in[7];
  const float* fc2w = (const float*)d_in[8];
  const float* fc2b = (const float*)d_in[9];

  char* ws = (char*)d_ws;
  u16* wbuf = (u16*)ws;
  u16* slt  = (u16*)ws;
  u16* wcum = (u16*)(ws + (size_t)(4 << 20));
  u16* h    = (u16*)(ws + (size_t)(8 << 20));
  u16* qkv  = (u16*)(ws + (size_t)(12 << 20));
  u16* f    = (u16*)(ws + (size_t)(12 << 20));
  u16* vt   = (u16*)(ws + (size_t)(24 << 20));
  u16* kt   = (u16*)(ws + (size_t)(28 << 20));
  float* xf = (float*)d_out;

  const int n8D = DD * DD / 8;
  const int n8F = DFFN * DD / 8;
  const int gInit = MM * DD / 4 / 256;   // 2048

  for (int i = 0; i < 2; i++) {
    const float* qwi  = qw   + (size_t)i * DD * DD;
    const float* kwi  = kw   + (size_t)i * DD * DD;
    const float* vwi  = vw   + (size_t)i * DD * DD;
    const float* owi  = ow   + (size_t)i * DD * DD;
    const float* fcwi = fcw  + (size_t)i * DFFN * DD;
    const float* f2wi = fc2w + (size_t)i * DD * DFFN;
    const float* src  = (i == 0) ? x_in : xf;

    rmsnorm_kernel<<<MM, 256, 0, stream>>>(src, pn + i * DD, h);
    // fused QKV projection: 256x128 tiles -> 192 blocks (1/CU, 8 waves)
    castw3_kernel<<<dim3(n8D / 256, 3), 256, 0, stream>>>(qwi, kwi, vwi, wbuf, n8D);
    mfma_gemm<256, 128, 0><<<dim3(QS / 128, MM / 256), 512, 0, stream>>>(
        h, wbuf, qkv, QS, DD);
    // chunked linear attention (a = h region)
    kv_trans<<<dim3(16, 32, BB), 256, 0, stream>>>(qkv, kt, vt);
    attn_phase1<<<dim3(16, HH, BB), 256, 0, stream>>>(qkv, kt, vt, h, slt);
    attn_phase2<<<dim3(8, HH, BB), 256, 0, stream>>>(slt, wcum);
    attn_phase3<<<dim3(16, HH, BB), 256, 0, stream>>>(qkv, wcum, h);
    // O-proj: xf = src + a @ ow^T  (256x128, split-K 4 -> 256 blocks)
    castw_kernel<<<n8D / 256, 256, 0, stream>>>(owi, wbuf, n8D);
    init_out_kernel<<<gInit, 256, 0, stream>>>(xf, src, nullptr);
    mfma_gemm_sk<256, 128, 4><<<dim3(DD / 128, MM / 256, 4), 512, 0, stream>>>(
        h, wbuf, xf, DD, DD);
    // MLP
    rmsnorm_kernel<<<MM, 256, 0, stream>>>(xf, ln + i * DD, h);
    castw_kernel<<<n8F / 256, 256, 0, stream>>>(fcwi, wbuf, n8F);
    // FC1: 256x128 tiles -> 256 blocks (1/CU, 8 waves)
    mfma_gemm<256, 128, 1><<<dim3(DFFN / 128, MM / 256), 512, 0, stream>>>(
        h, wbuf, f, DFFN, DD);
    castw_kernel<<<n8F / 256, 256, 0, stream>>>(f2wi, wbuf, n8F);
    float* co = (i == 1) ? (float*)d_out : xf;
    init_out_kernel<<<gInit, 256, 0, stream>>>(co, xf, fc2b + i * DD);
    // FC2: 256x128, split-K 4 -> 256 blocks (1/CU, 8 waves)
    mfma_gemm_sk<256, 128, 4><<<dim3(DD / 128, MM / 256, 4), 512, 0, stream>>>(
        f, wbuf, co, DD, DFFN);
  }
}

// Round 5
// 581.463 us; speedup vs baseline: 1.0715x; 1.0715x over previous
//
#include <hip/hip_runtime.h>

// Problem dims (fixed)
#define BB 2
#define LL 1024
#define DD 1024
#define HH 16
#define HD 64
#define DFFN 4096
#define MM (BB*LL)   // 2048 rows
#define QS 3072      // fused QKV row stride

using u16 = unsigned short;
typedef __bf16 bf16x8 __attribute__((ext_vector_type(8)));
typedef float f32x4 __attribute__((ext_vector_type(4)));

__device__ __forceinline__ float b2f(u16 u) {
  union { unsigned int i; float f; } v; v.i = ((unsigned int)u) << 16; return v.f;
}
__device__ __forceinline__ u16 f2b(float f) {
  union { float f; unsigned int i; } v; v.f = f;
  unsigned int x = v.i;
  return (u16)((x + 0x7fffu + ((x >> 16) & 1u)) >> 16);  // RNE, finite values
}
__device__ __forceinline__ float gelu_exact(float x) {
  return 0.5f * x * (1.0f + erff(x * 0.70710678118654752f));
}
__device__ __forceinline__ void gl2lds16(const void* g, void* l) {
  __builtin_amdgcn_global_load_lds((const __attribute__((address_space(1))) void*)g,
                                   (__attribute__((address_space(3))) void*)l, 16, 0, 0);
}

// counted waitcnt (T4): keep prefetch in flight; never drain to 0 mid-loop
template<int N>
__device__ __forceinline__ void s_wait_vm() {
  if constexpr (N == 0)       asm volatile("s_waitcnt vmcnt(0)" ::: "memory");
  else if constexpr (N == 3)  asm volatile("s_waitcnt vmcnt(3)" ::: "memory");
  else if constexpr (N == 6)  asm volatile("s_waitcnt vmcnt(6)" ::: "memory");
  __builtin_amdgcn_sched_barrier(0);
}

// T1: chunked XCD swizzle. HW assigns physical block b to XCD b%8 (round-robin).
// Remap so each group of 16 consecutive LOGICAL blocks (sharing an A-panel) lands
// on one XCD. Bijective when nb % 128 == 0 (grids that don't qualify -> identity).
__device__ __forceinline__ void xcd_remap(int& bx, int& by, int& bz) {
  const int gx = gridDim.x, gy = gridDim.y;
  const int nb = gx * gy * gridDim.z;
  int b = blockIdx.x + gx * (blockIdx.y + gy * blockIdx.z);
  if ((nb & 127) == 0) {
    const int xcd = b & 7, seq = b >> 3;
    b = (((seq >> 4) << 3) + xcd) * 16 + (seq & 15);
  }
  bx = b % gx; const int rest = b / gx;
  by = rest % gy; bz = rest / gy;
}

// ---------------- weight casts fp32 -> bf16 ----------------
__global__ __launch_bounds__(256) void castw_kernel(const float* __restrict__ in,
                                                    u16* __restrict__ out, int n8) {
  int i = blockIdx.x * 256 + threadIdx.x;
  if (i >= n8) return;
  const float4 a = reinterpret_cast<const float4*>(in)[2 * i];
  const float4 b = reinterpret_cast<const float4*>(in)[2 * i + 1];
  uint4 o;
  o.x = (unsigned)f2b(a.x) | ((unsigned)f2b(a.y) << 16);
  o.y = (unsigned)f2b(a.z) | ((unsigned)f2b(a.w) << 16);
  o.z = (unsigned)f2b(b.x) | ((unsigned)f2b(b.y) << 16);
  o.w = (unsigned)f2b(b.z) | ((unsigned)f2b(b.w) << 16);
  reinterpret_cast<uint4*>(out)[i] = o;
}
__global__ __launch_bounds__(256) void castw3_kernel(const float* __restrict__ s0,
                                                     const float* __restrict__ s1,
                                                     const float* __restrict__ s2,
                                                     u16* __restrict__ out, int n8) {
  int i = blockIdx.x * 256 + threadIdx.x;
  if (i >= n8) return;
  const float* in = (blockIdx.y == 0) ? s0 : (blockIdx.y == 1) ? s1 : s2;
  u16* dst = out + (size_t)blockIdx.y * n8 * 8;
  const float4 a = reinterpret_cast<const float4*>(in)[2 * i];
  const float4 b = reinterpret_cast<const float4*>(in)[2 * i + 1];
  uint4 o;
  o.x = (unsigned)f2b(a.x) | ((unsigned)f2b(a.y) << 16);
  o.y = (unsigned)f2b(a.z) | ((unsigned)f2b(a.w) << 16);
  o.z = (unsigned)f2b(b.x) | ((unsigned)f2b(b.y) << 16);
  o.w = (unsigned)f2b(b.z) | ((unsigned)f2b(b.w) << 16);
  reinterpret_cast<uint4*>(dst)[i] = o;
}

// ---------------- out = resid (+ bias), fp32 ----------------
__global__ __launch_bounds__(256) void init_out_kernel(float* __restrict__ out,
                                                       const float* __restrict__ resid,
                                                       const float* __restrict__ bias) {
  const int i = blockIdx.x * 256 + threadIdx.x;   // float4 index
  float4 v = reinterpret_cast<const float4*>(resid)[i];
  if (bias != nullptr) {
    const float4 bv = *reinterpret_cast<const float4*>(bias + ((i * 4) & (DD - 1)));
    v.x += bv.x; v.y += bv.y; v.z += bv.z; v.w += bv.w;
  }
  reinterpret_cast<float4*>(out)[i] = v;
}

// ---------------- rmsnorm (fp32 in, fp32 weight, bf16 out) ----------------
__global__ __launch_bounds__(256) void rmsnorm_kernel(const float* __restrict__ x,
                                                      const float* __restrict__ w,
                                                      u16* __restrict__ out) {
  const int row = blockIdx.x, t = threadIdx.x;
  const float4 v = reinterpret_cast<const float4*>(x + (size_t)row * DD)[t];
  float ss = v.x*v.x + v.y*v.y + v.z*v.z + v.w*v.w;
  #pragma unroll
  for (int o = 32; o > 0; o >>= 1) ss += __shfl_down(ss, o);
  __shared__ float red[4];
  if ((t & 63) == 0) red[t >> 6] = ss;
  __syncthreads();
  const float inv = rsqrtf((red[0] + red[1] + red[2] + red[3]) * (1.0f / DD) + 1e-5f);
  const float4 wv = reinterpret_cast<const float4*>(w)[t];
  ushort4 o;
  o.x = f2b(v.x * inv * wv.x);
  o.y = f2b(v.y * inv * wv.y);
  o.z = f2b(v.z * inv * wv.z);
  o.w = f2b(v.w * inv * wv.w);
  reinterpret_cast<ushort4*>(out + (size_t)row * DD)[t] = o;
}

// ---- BK=32 staging with bank-conflict-free chunk permutation ----
// 16B chunk of logical (row r, kchunk q) lives at LDS slot
//   p = (r&7) | (q<<3) | ((r>>3)<<5)
// Verified R4: SQ_LDS_BANK_CONFLICT 2.1M -> 0. dma inverts the permutation on the
// GLOBAL address; each wave still covers 16 full 64B lines -> coalescing preserved.
template<int ROWS, int NT>
__device__ __forceinline__ void dma32(const u16* __restrict__ g, int r0, int K, int kt,
                                      int t, u16* lds) {
  #pragma unroll
  for (int i = 0; i < ROWS * 4 / NT; i++) {
    const int c = i * NT + t;
    const int row = (c & 7) | ((c >> 5) << 3);
    const int kc = (c >> 3) & 3;
    gl2lds16(g + (size_t)(r0 + row) * K + kt + kc * 8, &lds[c * 8]);
  }
}
__device__ __forceinline__ const bf16x8* lds_frag(const u16* base, int r, int fq) {
  const int p = (r & 7) | (fq << 3) | ((r >> 3) << 5);
  return reinterpret_cast<const bf16x8*>(&base[p * 8]);
}

#define MFMA_BF16 __builtin_amdgcn_mfma_f32_16x16x32_bf16

// ---- m201-style phased pipeline (T3+T4+T5) on 256x128, BK=32, 4 buffers ----
// Per K-tile, 2 phases. CRITICAL ordering (the R2-R4 defect): ds_reads are issued
// BEFORE the phase's global_load_lds, so no fragment read ever follows an
// un-retired DMA in program order (compiler cannot re-serialize with vmcnt(0)).
// Boundary vmcnt sits BEFORE a barrier: per-wave retire + all-waves guarantee.
// WAR safety: stage(t+3) targets buf (pb-1), whose reads all retired at the
// previous boundary barrier (each wave: ds_read -> lgkmcnt(0) -> MFMA -> barrier).
template<int BM, int BN>
__device__ __forceinline__ void gemm_pipe(const u16* __restrict__ A,
                                          const u16* __restrict__ Wb,
                                          int K, int k0, int nt, int m0, int n0,
                                          u16* As, u16* Bs, int t,
                                          int wm, int wn, int fr, int fq,
                                          f32x4 acc[4][4]) {
  constexpr int NT = (BM / 64) * (BN / 64) * 64;   // 512
  // prologue: stage tiles 0..2 (nt >= 4 in all our shapes), retire stage 0
  #pragma unroll
  for (int s = 0; s < 3; ++s) {
    dma32<BM, NT>(A, m0, K, k0 + s * 32, t, As + s * BM * 32);
    dma32<BN, NT>(Wb, n0, K, k0 + s * 32, t, Bs + s * BN * 32);
  }
  s_wait_vm<6>();
  __builtin_amdgcn_s_barrier();
  int pb = 0;
  for (int tt = 0; tt < nt; ++tt) {
    const u16* Asb = As + pb * BM * 32;
    const u16* Bsb = Bs + pb * BN * 32;
    const int p3 = (pb + 3) & 3;
    const bool st = (tt + 3 < nt);     // wave-uniform
    // ======== phase A: frag reads FIRST, then stage-issue ========
    bf16x8 a0 = *lds_frag(Asb, wm + 0 * 16 + fr, fq);
    bf16x8 a1 = *lds_frag(Asb, wm + 1 * 16 + fr, fq);
    bf16x8 b0 = *lds_frag(Bsb, wn + 0 * 16 + fr, fq);
    bf16x8 b1 = *lds_frag(Bsb, wn + 1 * 16 + fr, fq);
    bf16x8 b2 = *lds_frag(Bsb, wn + 2 * 16 + fr, fq);
    bf16x8 b3 = *lds_frag(Bsb, wn + 3 * 16 + fr, fq);
    if (st) dma32<BM, NT>(A, m0, K, k0 + (tt + 3) * 32, t, As + p3 * BM * 32);
    __builtin_amdgcn_sched_barrier(0);
    __builtin_amdgcn_s_barrier();
    asm volatile("s_waitcnt lgkmcnt(0)" ::: "memory");
    __builtin_amdgcn_sched_barrier(0);
    __builtin_amdgcn_s_setprio(1);
    acc[0][0] = MFMA_BF16(a0, b0, acc[0][0], 0, 0, 0);
    acc[0][1] = MFMA_BF16(a0, b1, acc[0][1], 0, 0, 0);
    acc[0][2] = MFMA_BF16(a0, b2, acc[0][2], 0, 0, 0);
    acc[0][3] = MFMA_BF16(a0, b3, acc[0][3], 0, 0, 0);
    acc[1][0] = MFMA_BF16(a1, b0, acc[1][0], 0, 0, 0);
    acc[1][1] = MFMA_BF16(a1, b1, acc[1][1], 0, 0, 0);
    acc[1][2] = MFMA_BF16(a1, b2, acc[1][2], 0, 0, 0);
    acc[1][3] = MFMA_BF16(a1, b3, acc[1][3], 0, 0, 0);
    __builtin_amdgcn_s_setprio(0);
    __builtin_amdgcn_sched_barrier(0);
    __builtin_amdgcn_s_barrier();
    // ======== phase B ========
    bf16x8 a2 = *lds_frag(Asb, wm + 2 * 16 + fr, fq);
    bf16x8 a3 = *lds_frag(Asb, wm + 3 * 16 + fr, fq);
    if (st) dma32<BN, NT>(Wb, n0, K, k0 + (tt + 3) * 32, t, Bs + p3 * BN * 32);
    __builtin_amdgcn_sched_barrier(0);
    __builtin_amdgcn_s_barrier();
    asm volatile("s_waitcnt lgkmcnt(0)" ::: "memory");
    __builtin_amdgcn_sched_barrier(0);
    __builtin_amdgcn_s_setprio(1);
    acc[2][0] = MFMA_BF16(a2, b0, acc[2][0], 0, 0, 0);
    acc[2][1] = MFMA_BF16(a2, b1, acc[2][1], 0, 0, 0);
    acc[2][2] = MFMA_BF16(a2, b2, acc[2][2], 0, 0, 0);
    acc[2][3] = MFMA_BF16(a2, b3, acc[2][3], 0, 0, 0);
    acc[3][0] = MFMA_BF16(a3, b0, acc[3][0], 0, 0, 0);
    acc[3][1] = MFMA_BF16(a3, b1, acc[3][1], 0, 0, 0);
    acc[3][2] = MFMA_BF16(a3, b2, acc[3][2], 0, 0, 0);
    acc[3][3] = MFMA_BF16(a3, b3, acc[3][3], 0, 0, 0);
    __builtin_amdgcn_s_setprio(0);
    __builtin_amdgcn_sched_barrier(0);
    // ======== tile boundary: retire stage(tt+1); barrier = all-waves landed ====
    if (tt + 1 < nt) {
      const int rem = nt - 2 - tt;     // stages still wanted in flight
      if (rem >= 2)      s_wait_vm<6>();
      else if (rem == 1) s_wait_vm<3>();
      else               s_wait_vm<0>();
      __builtin_amdgcn_s_barrier();
    }
    pb = (pb + 1) & 3;
  }
}

// ---------------- MFMA GEMM: C[M,N](bf16) = A(bf16) @ Wb(bf16,[N,K])^T ----------------
// 256x128 tile, 8 waves (4M x 2N, per-wave 64x64), phased pipeline.
template<int BM, int BN, int ACT>
__global__ __launch_bounds__((BM/64)*(BN/64)*64)
void mfma_gemm(const u16* __restrict__ A, const u16* __restrict__ Wb,
               u16* __restrict__ Cb, int N, int K) {
  constexpr int WCOLS = BN / 64;
  __shared__ u16 As[4 * BM * 32];
  __shared__ u16 Bs[4 * BN * 32];
  int bx, by, bz;
  xcd_remap(bx, by, bz);
  const int t = threadIdx.x;
  const int lane = t & 63, w = t >> 6;
  const int wm = (w / WCOLS) * 64, wn = (w % WCOLS) * 64;
  const int m0 = by * BM, n0 = bx * BN;
  const int fr = lane & 15, fq = lane >> 4;

  f32x4 acc[4][4] = {};
  gemm_pipe<BM, BN>(A, Wb, K, 0, K / 32, m0, n0, As, Bs, t, wm, wn, fr, fq, acc);

  #pragma unroll
  for (int i = 0; i < 4; i++)
    #pragma unroll
    for (int j = 0; j < 4; j++)
      #pragma unroll
      for (int r = 0; r < 4; r++) {
        const int row = m0 + wm + i * 16 + fq * 4 + r;
        const int col = n0 + wn + j * 16 + fr;
        float val = acc[i][j][r];
        if (ACT == 1) val = gelu_exact(val);
        Cb[(size_t)row * N + col] = f2b(val);
      }
}

// ---------------- split-K MFMA GEMM: Co(f32) += A @ Wb^T  (Co pre-initialized) ----------------
template<int BM, int BN, int SPLIT>
__global__ __launch_bounds__((BM/64)*(BN/64)*64)
void mfma_gemm_sk(const u16* __restrict__ A, const u16* __restrict__ Wb,
                  float* __restrict__ Co, int N, int K) {
  constexpr int WCOLS = BN / 64;
  __shared__ u16 As[4 * BM * 32];
  __shared__ u16 Bs[4 * BN * 32];
  int bx, by, bz;
  xcd_remap(bx, by, bz);
  const int t = threadIdx.x;
  const int lane = t & 63, w = t >> 6;
  const int wm = (w / WCOLS) * 64, wn = (w % WCOLS) * 64;
  const int m0 = by * BM, n0 = bx * BN;
  const int fr = lane & 15, fq = lane >> 4;
  const int Kc = K / SPLIT, k0 = bz * Kc;

  f32x4 acc[4][4] = {};
  gemm_pipe<BM, BN>(A, Wb, K, k0, Kc / 32, m0, n0, As, Bs, t, wm, wn, fr, fq, acc);

  #pragma unroll
  for (int i = 0; i < 4; i++)
    #pragma unroll
    for (int j = 0; j < 4; j++)
      #pragma unroll
      for (int r = 0; r < 4; r++) {
        const int row = m0 + wm + i * 16 + fq * 4 + r;
        const int col = n0 + wn + j * 16 + fr;
        unsafeAtomicAdd(&Co[(size_t)row * N + col], acc[i][j][r]);
      }
}

// ---------------- K/V transpose via LDS, coalesced both sides ----------------
__global__ __launch_bounds__(256) void kv_trans(const u16* __restrict__ QKV,
                                                u16* __restrict__ Kt, u16* __restrict__ Vt) {
  __shared__ u16 T[64][72];
  const int tile = blockIdx.x;
  const int h2 = blockIdx.y;             // h = h2&15, which = h2>>4 (0=K, 1=V)
  const int b = blockIdx.z;
  const int h = h2 & 15, which = h2 >> 4;
  const int t = threadIdx.x;
  const int pos = t >> 2, d0 = (t & 3) * 16;
  const u16* src = QKV + ((size_t)(b * LL) + tile * 64 + pos) * QS + 1024 + which * 1024 + h * HD + d0;
  union { uint4 u[2]; u16 s[16]; } pk;
  pk.u[0] = reinterpret_cast<const uint4*>(src)[0];
  pk.u[1] = reinterpret_cast<const uint4*>(src)[1];
  #pragma unroll
  for (int j = 0; j < 16; j++) T[d0 + j][pos] = pk.s[j];
  __syncthreads();
  const int d = t >> 2, p0 = (t & 3) * 16;
  u16* dst = (which ? Vt : Kt) + ((size_t)(b * HH + h) * HD + d) * LL + tile * 64 + p0;
  union { uint4 u[2]; u16 s[16]; } ok;
  #pragma unroll
  for (int j = 0; j < 16; j++) ok.s[j] = T[d][p0 + j];
  reinterpret_cast<uint4*>(dst)[0] = ok.u[0];
  reinterpret_cast<uint4*>(dst)[1] = ok.u[1];
}

// ---------------- attention phase 1 ----------------
__global__ __launch_bounds__(256) void attn_phase1(const u16* __restrict__ QKV,
                                                   const u16* __restrict__ Kt,
                                                   const u16* __restrict__ Vt,
                                                   u16* __restrict__ Oa,
                                                   u16* __restrict__ Slt) {
  __shared__ u16 Ss[4][16][64];
  const int tile = blockIdx.x, h = blockIdx.y, b = blockIdx.z;
  const int t = threadIdx.x, lane = t & 63, w = t >> 6;
  const int fr = lane & 15, fq = lane >> 4;
  const size_t tok0 = (size_t)(b * LL + tile * 64);
  const size_t bh = (size_t)(b * HH + h);
  const u16* Qb  = QKV + tok0 * QS + h * HD;
  const u16* Kb  = Qb + 1024;
  const u16* Ktb = Kt + bh * (HD * LL) + tile * 64;
  const u16* Vtb = Vt + bh * (HD * LL) + tile * 64;

  // ---- S = Q K^T ----
  bf16x8 aq[2], bk[4][2];
  #pragma unroll
  for (int kh = 0; kh < 2; kh++)
    aq[kh] = *reinterpret_cast<const bf16x8*>(Qb + (size_t)(16*w + fr) * QS + kh*32 + fq*8);
  #pragma unroll
  for (int n4 = 0; n4 < 4; n4++)
    #pragma unroll
    for (int kh = 0; kh < 2; kh++)
      bk[n4][kh] = *reinterpret_cast<const bf16x8*>(Kb + (size_t)(16*n4 + fr) * QS + kh*32 + fq*8);
  f32x4 sacc[4] = {};
  #pragma unroll
  for (int n4 = 0; n4 < 4; n4++) {
    sacc[n4] = MFMA_BF16(aq[0], bk[n4][0], sacc[n4], 0, 0, 0);
    sacc[n4] = MFMA_BF16(aq[1], bk[n4][1], sacc[n4], 0, 0, 0);
  }
  #pragma unroll
  for (int n4 = 0; n4 < 4; n4++)
    #pragma unroll
    for (int r = 0; r < 4; r++) {
      const bool keep = (16*w + 4*fq + r) >= (16*n4 + fr);
      Ss[w][4*fq + r][16*n4 + fr] = keep ? f2b(sacc[n4][r]) : (u16)0;
    }
  __syncthreads();

  // ---- Slt = V^T K ----
  bf16x8 va[2], kt[4][2];
  #pragma unroll
  for (int kh = 0; kh < 2; kh++)
    va[kh] = *reinterpret_cast<const bf16x8*>(Vtb + (size_t)(16*w + fr) * LL + kh*32 + fq*8);
  #pragma unroll
  for (int n4 = 0; n4 < 4; n4++)
    #pragma unroll
    for (int kh = 0; kh < 2; kh++)
      kt[n4][kh] = *reinterpret_cast<const bf16x8*>(Ktb + (size_t)(16*n4 + fr) * LL + kh*32 + fq*8);
  f32x4 lacc[4] = {};
  #pragma unroll
  for (int n4 = 0; n4 < 4; n4++) {
    lacc[n4] = MFMA_BF16(va[0], kt[n4][0], lacc[n4], 0, 0, 0);
    lacc[n4] = MFMA_BF16(va[1], kt[n4][1], lacc[n4], 0, 0, 0);
  }
  u16* So = Slt + (bh * 16 + tile) * 4096;
  #pragma unroll
  for (int n4 = 0; n4 < 4; n4++)
    #pragma unroll
    for (int r = 0; r < 4; r++)
      So[(size_t)(16*w + 4*fq + r) * 64 + 16*n4 + fr] = f2b(lacc[n4][r]);

  // ---- O_intra = S V ----
  bf16x8 sa[2], vb[4][2];
  #pragma unroll
  for (int kh = 0; kh < 2; kh++)
    sa[kh] = *reinterpret_cast<const bf16x8*>(&Ss[w][fr][kh*32 + fq*8]);
  #pragma unroll
  for (int n4 = 0; n4 < 4; n4++)
    #pragma unroll
    for (int kh = 0; kh < 2; kh++)
      vb[n4][kh] = *reinterpret_cast<const bf16x8*>(Vtb + (size_t)(16*n4 + fr) * LL + kh*32 + fq*8);
  f32x4 oacc[4] = {};
  #pragma unroll
  for (int n4 = 0; n4 < 4; n4++) {
    oacc[n4] = MFMA_BF16(sa[0], vb[n4][0], oacc[n4], 0, 0, 0);
    oacc[n4] = MFMA_BF16(sa[1], vb[n4][1], oacc[n4], 0, 0, 0);
  }
  u16* Ob = Oa + (tok0 + 16*w) * DD + h * HD;
  #pragma unroll
  for (int n4 = 0; n4 < 4; n4++)
    #pragma unroll
    for (int r = 0; r < 4; r++)
      Ob[(size_t)(4*fq + r) * DD + 16*n4 + fr] = f2b(oacc[n4][r]);
}

// ---------------- attention phase 2: exclusive fp32 scan ----------------
__global__ __launch_bounds__(256) void attn_phase2(const u16* __restrict__ Slt,
                                                   u16* __restrict__ Wc) {
  const int rg = blockIdx.x, h = blockIdx.y, b = blockIdx.z;
  const size_t base = ((size_t)((b * HH + h) * 16)) * 4096 + rg * 512 + threadIdx.x * 2;
  float r0 = 0.f, r1 = 0.f;
  for (int tl = 0; tl < 16; tl++) {
    const size_t p = base + (size_t)tl * 4096;
    const unsigned d = *reinterpret_cast<const unsigned*>(Slt + p);
    *reinterpret_cast<unsigned*>(Wc + p) = (unsigned)f2b(r0) | ((unsigned)f2b(r1) << 16);
    r0 += b2f((u16)(d & 0xffff));
    r1 += b2f((u16)(d >> 16));
  }
}

// ---------------- attention phase 3: O += Q @ W_prev ----------------
__global__ __launch_bounds__(256) void attn_phase3(const u16* __restrict__ QKV,
                                                   const u16* __restrict__ Wc,
                                                   u16* __restrict__ Oa) {
  const int tile = blockIdx.x, h = blockIdx.y, b = blockIdx.z;
  const int t = threadIdx.x, lane = t & 63, w = t >> 6;
  const int fr = lane & 15, fq = lane >> 4;
  const size_t tok0 = (size_t)(b * LL + tile * 64);
  const size_t bh = (size_t)(b * HH + h);
  const u16* Qb = QKV + tok0 * QS + h * HD;
  const u16* Wb = Wc + (bh * 16 + tile) * 4096;

  bf16x8 aq[2], wb[4][2];
  #pragma unroll
  for (int kh = 0; kh < 2; kh++)
    aq[kh] = *reinterpret_cast<const bf16x8*>(Qb + (size_t)(16*w + fr) * QS + kh*32 + fq*8);
  #pragma unroll
  for (int n4 = 0; n4 < 4; n4++)
    #pragma unroll
    for (int kh = 0; kh < 2; kh++)
      wb[n4][kh] = *reinterpret_cast<const bf16x8*>(Wb + (size_t)(16*n4 + fr) * 64 + kh*32 + fq*8);
  f32x4 oacc[4] = {};
  #pragma unroll
  for (int n4 = 0; n4 < 4; n4++) {
    oacc[n4] = MFMA_BF16(aq[0], wb[n4][0], oacc[n4], 0, 0, 0);
    oacc[n4] = MFMA_BF16(aq[1], wb[n4][1], oacc[n4], 0, 0, 0);
  }
  u16* Ob = Oa + (tok0 + 16*w) * DD + h * HD;
  #pragma unroll
  for (int n4 = 0; n4 < 4; n4++)
    #pragma unroll
    for (int r = 0; r < 4; r++) {
      const size_t idx = (size_t)(4*fq + r) * DD + 16*n4 + fr;
      Ob[idx] = f2b(b2f(Ob[idx]) + oacc[n4][r]);
    }
}

// ---------------- host ----------------
// ws map (32 MB): wbuf 0..8 (time-shared with Slt 0..4 / Wcum 4..8 during attn)
// h/a/m 8..12 | qkv 12..24 | f 12..28 (qkv/Vt dead) | Vt 24..28 | Kt 28..32
// fp32 residual stream lives in d_out.
extern "C" void kernel_launch(void* const* d_in, const int* in_sizes, int n_in,
                              void* d_out, int out_size, void* d_ws, size_t ws_size,
                              hipStream_t stream) {
  const float* x_in = (const float*)d_in[0];
  const float* qw   = (const float*)d_in[1];
  const float* kw   = (const float*)d_in[2];
  const float* vw   = (const float*)d_in[3];
  const float* ow   = (const float*)d_in[4];
  const float* pn   = (const float*)d_in[5];
  const float* ln   = (const float*)d_in[6];
  const float* fcw  = (const float*)d_in[7];
  const float* fc2w = (const float*)d_in[8];
  const float* fc2b = (const float*)d_in[9];

  char* ws = (char*)d_ws;
  u16* wbuf = (u16*)ws;
  u16* slt  = (u16*)ws;
  u16* wcum = (u16*)(ws + (size_t)(4 << 20));
  u16* h    = (u16*)(ws + (size_t)(8 << 20));
  u16* qkv  = (u16*)(ws + (size_t)(12 << 20));
  u16* f    = (u16*)(ws + (size_t)(12 << 20));
  u16* vt   = (u16*)(ws + (size_t)(24 << 20));
  u16* kt   = (u16*)(ws + (size_t)(28 << 20));
  float* xf = (float*)d_out;

  const int n8D = DD * DD / 8;
  const int n8F = DFFN * DD / 8;
  const int gInit = MM * DD / 4 / 256;   // 2048

  for (int i = 0; i < 2; i++) {
    const float* qwi  = qw   + (size_t)i * DD * DD;
    const float* kwi  = kw   + (size_t)i * DD * DD;
    const float* vwi  = vw   + (size_t)i * DD * DD;
    const float* owi  = ow   + (size_t)i * DD * DD;
    const float* fcwi = fcw  + (size_t)i * DFFN * DD;
    const float* f2wi = fc2w + (size_t)i * DD * DFFN;
    const float* src  = (i == 0) ? x_in : xf;

    rmsnorm_kernel<<<MM, 256, 0, stream>>>(src, pn + i * DD, h);
    // fused QKV projection: 256x128 tiles -> 192 blocks, phased pipeline
    castw3_kernel<<<dim3(n8D / 256, 3), 256, 0, stream>>>(qwi, kwi, vwi, wbuf, n8D);
    mfma_gemm<256, 128, 0><<<dim3(QS / 128, MM / 256), 512, 0, stream>>>(
        h, wbuf, qkv, QS, DD);
    // chunked linear attention (a = h region)
    kv_trans<<<dim3(16, 32, BB), 256, 0, stream>>>(qkv, kt, vt);
    attn_phase1<<<dim3(16, HH, BB), 256, 0, stream>>>(qkv, kt, vt, h, slt);
    attn_phase2<<<dim3(8, HH, BB), 256, 0, stream>>>(slt, wcum);
    attn_phase3<<<dim3(16, HH, BB), 256, 0, stream>>>(qkv, wcum, h);
    // O-proj: xf = src + a @ ow^T  (256x128, split-K 4 -> 256 blocks)
    castw_kernel<<<n8D / 256, 256, 0, stream>>>(owi, wbuf, n8D);
    init_out_kernel<<<gInit, 256, 0, stream>>>(xf, src, nullptr);
    mfma_gemm_sk<256, 128, 4><<<dim3(DD / 128, MM / 256, 4), 512, 0, stream>>>(
        h, wbuf, xf, DD, DD);
    // MLP
    rmsnorm_kernel<<<MM, 256, 0, stream>>>(xf, ln + i * DD, h);
    castw_kernel<<<n8F / 256, 256, 0, stream>>>(fcwi, wbuf, n8F);
    // FC1: 256x128 tiles -> 256 blocks, phased pipeline
    mfma_gemm<256, 128, 1><<<dim3(DFFN / 128, MM / 256), 512, 0, stream>>>(
        h, wbuf, f, DFFN, DD);
    castw_kernel<<<n8F / 256, 256, 0, stream>>>(f2wi, wbuf, n8F);
    float* co = (i == 1) ? (float*)d_out : xf;
    init_out_kernel<<<gInit, 256, 0, stream>>>(co, xf, fc2b + i * DD);
    // FC2: 256x128, split-K 4 -> 256 blocks, phased pipeline
    mfma_gemm_sk<256, 128, 4><<<dim3(DD / 128, MM / 256, 4), 512, 0, stream>>>(
        f, wbuf, co, DD, DFFN);
  }
}

// Round 6
// 571.071 us; speedup vs baseline: 1.0910x; 1.0182x over previous
//
#include <hip/hip_runtime.h>

// Problem dims (fixed)
#define BB 2
#define LL 1024
#define DD 1024
#define HH 16
#define HD 64
#define DFFN 4096
#define MM (BB*LL)   // 2048 rows
#define QS 3072      // fused QKV row stride

using u16 = unsigned short;
typedef __bf16 bf16x8 __attribute__((ext_vector_type(8)));
typedef float f32x4 __attribute__((ext_vector_type(4)));

__device__ __forceinline__ float b2f(u16 u) {
  union { unsigned int i; float f; } v; v.i = ((unsigned int)u) << 16; return v.f;
}
__device__ __forceinline__ u16 f2b(float f) {
  union { float f; unsigned int i; } v; v.f = f;
  unsigned int x = v.i;
  return (u16)((x + 0x7fffu + ((x >> 16) & 1u)) >> 16);  // RNE, finite values
}
__device__ __forceinline__ float gelu_exact(float x) {
  return 0.5f * x * (1.0f + erff(x * 0.70710678118654752f));
}
__device__ __forceinline__ void gl2lds16(const void* g, void* l) {
  __builtin_amdgcn_global_load_lds((const __attribute__((address_space(1))) void*)g,
                                   (__attribute__((address_space(3))) void*)l, 16, 0, 0);
}

// counted waitcnt (T4): keep prefetch in flight; never drain to 0 mid-loop
template<int N>
__device__ __forceinline__ void s_wait_vm() {
  if constexpr (N == 0)       asm volatile("s_waitcnt vmcnt(0)" ::: "memory");
  else if constexpr (N == 3)  asm volatile("s_waitcnt vmcnt(3)" ::: "memory");
  else if constexpr (N == 6)  asm volatile("s_waitcnt vmcnt(6)" ::: "memory");
  else if constexpr (N == 12) asm volatile("s_waitcnt vmcnt(12)" ::: "memory");
  __builtin_amdgcn_sched_barrier(0);
}

// T1: chunked XCD swizzle. HW assigns physical block b to XCD b%8 (round-robin).
// Remap so each group of 16 consecutive LOGICAL blocks (sharing an A-panel) lands
// on one XCD. Bijective when nb % 128 == 0 (grids that don't qualify -> identity).
__device__ __forceinline__ void xcd_remap(int& bx, int& by, int& bz) {
  const int gx = gridDim.x, gy = gridDim.y;
  const int nb = gx * gy * gridDim.z;
  int b = blockIdx.x + gx * (blockIdx.y + gy * blockIdx.z);
  if ((nb & 127) == 0) {
    const int xcd = b & 7, seq = b >> 3;
    b = (((seq >> 4) << 3) + xcd) * 16 + (seq & 15);
  }
  bx = b % gx; const int rest = b / gx;
  by = rest % gy; bz = rest / gy;
}

// ---------------- weight casts fp32 -> bf16 ----------------
__global__ __launch_bounds__(256) void castw_kernel(const float* __restrict__ in,
                                                    u16* __restrict__ out, int n8) {
  int i = blockIdx.x * 256 + threadIdx.x;
  if (i >= n8) return;
  const float4 a = reinterpret_cast<const float4*>(in)[2 * i];
  const float4 b = reinterpret_cast<const float4*>(in)[2 * i + 1];
  uint4 o;
  o.x = (unsigned)f2b(a.x) | ((unsigned)f2b(a.y) << 16);
  o.y = (unsigned)f2b(a.z) | ((unsigned)f2b(a.w) << 16);
  o.z = (unsigned)f2b(b.x) | ((unsigned)f2b(b.y) << 16);
  o.w = (unsigned)f2b(b.z) | ((unsigned)f2b(b.w) << 16);
  reinterpret_cast<uint4*>(out)[i] = o;
}
__global__ __launch_bounds__(256) void castw3_kernel(const float* __restrict__ s0,
                                                     const float* __restrict__ s1,
                                                     const float* __restrict__ s2,
                                                     u16* __restrict__ out, int n8) {
  int i = blockIdx.x * 256 + threadIdx.x;
  if (i >= n8) return;
  const float* in = (blockIdx.y == 0) ? s0 : (blockIdx.y == 1) ? s1 : s2;
  u16* dst = out + (size_t)blockIdx.y * n8 * 8;
  const float4 a = reinterpret_cast<const float4*>(in)[2 * i];
  const float4 b = reinterpret_cast<const float4*>(in)[2 * i + 1];
  uint4 o;
  o.x = (unsigned)f2b(a.x) | ((unsigned)f2b(a.y) << 16);
  o.y = (unsigned)f2b(a.z) | ((unsigned)f2b(a.w) << 16);
  o.z = (unsigned)f2b(b.x) | ((unsigned)f2b(b.y) << 16);
  o.w = (unsigned)f2b(b.z) | ((unsigned)f2b(b.w) << 16);
  reinterpret_cast<uint4*>(dst)[i] = o;
}

// ---------------- rmsnorm (fp32 in, fp32 weight, bf16 out) ----------------
__global__ __launch_bounds__(256) void rmsnorm_kernel(const float* __restrict__ x,
                                                      const float* __restrict__ w,
                                                      u16* __restrict__ out) {
  const int row = blockIdx.x, t = threadIdx.x;
  const float4 v = reinterpret_cast<const float4*>(x + (size_t)row * DD)[t];
  float ss = v.x*v.x + v.y*v.y + v.z*v.z + v.w*v.w;
  #pragma unroll
  for (int o = 32; o > 0; o >>= 1) ss += __shfl_down(ss, o);
  __shared__ float red[4];
  if ((t & 63) == 0) red[t >> 6] = ss;
  __syncthreads();
  const float inv = rsqrtf((red[0] + red[1] + red[2] + red[3]) * (1.0f / DD) + 1e-5f);
  const float4 wv = reinterpret_cast<const float4*>(w)[t];
  ushort4 o;
  o.x = f2b(v.x * inv * wv.x);
  o.y = f2b(v.y * inv * wv.y);
  o.z = f2b(v.z * inv * wv.z);
  o.w = f2b(v.w * inv * wv.w);
  reinterpret_cast<ushort4*>(out + (size_t)row * DD)[t] = o;
}

// ---------------- reduce: co += P (P split in two 4MB halves) ----------------
__global__ __launch_bounds__(256) void reduce_add_kernel(float* __restrict__ co,
                                                         const float* __restrict__ P0,
                                                         const float* __restrict__ P1) {
  const int i = blockIdx.x * 256 + threadIdx.x;   // float4 index, 0..524287
  constexpr int HALF = (MM / 2) * DD / 4;         // 262144 float4 per half
  const float4 p = (i < HALF) ? reinterpret_cast<const float4*>(P0)[i]
                              : reinterpret_cast<const float4*>(P1)[i - HALF];
  float4 v = reinterpret_cast<float4*>(co)[i];
  v.x += p.x; v.y += p.y; v.z += p.z; v.w += p.w;
  reinterpret_cast<float4*>(co)[i] = v;
}

// ---- BK=32 staging with bank-conflict-free chunk permutation ----
// 16B chunk of logical (row r, kchunk q) lives at LDS slot
//   p = (r&7) | (q<<3) | ((r>>3)<<5)
// Verified R4: SQ_LDS_BANK_CONFLICT 2.1M -> 0. dma inverts the permutation on the
// GLOBAL address; each wave still covers 16 full 64B lines -> coalescing preserved.
template<int ROWS, int NT>
__device__ __forceinline__ void dma32(const u16* __restrict__ g, int r0, int K, int kt,
                                      int t, u16* lds) {
  #pragma unroll
  for (int i = 0; i < ROWS * 4 / NT; i++) {
    const int c = i * NT + t;
    const int row = (c & 7) | ((c >> 5) << 3);
    const int kc = (c >> 3) & 3;
    gl2lds16(g + (size_t)(r0 + row) * K + kt + kc * 8, &lds[c * 8]);
  }
}
__device__ __forceinline__ const bf16x8* lds_frag(const u16* base, int r, int fq) {
  const int p = (r & 7) | (fq << 3) | ((r >> 3) << 5);
  return reinterpret_cast<const bf16x8*>(&base[p * 8]);
}

#define MFMA_BF16 __builtin_amdgcn_mfma_f32_16x16x32_bf16

// ---- phased pipeline (T3+T4+T5), BK=32, 4 LDS buffers ----
// Per K-tile, 2 phases; ds_reads issued BEFORE the phase's global_load_lds;
// boundary counted-vmcnt sits BEFORE a barrier (per-wave retire -> all-waves).
template<int BM, int BN>
__device__ __forceinline__ void gemm_pipe(const u16* __restrict__ A,
                                          const u16* __restrict__ Wb,
                                          int K, int k0, int nt, int m0, int n0,
                                          u16* As, u16* Bs, int t,
                                          int wm, int wn, int fr, int fq,
                                          f32x4 acc[4][4]) {
  constexpr int NT = (BM / 64) * (BN / 64) * 64;
  constexpr int LT = (BM + BN) * 4 / NT;   // loads/thread/tile
  // prologue: stage tiles 0..2 (nt >= 4 in all our shapes), retire stage 0
  #pragma unroll
  for (int s = 0; s < 3; ++s) {
    dma32<BM, NT>(A, m0, K, k0 + s * 32, t, As + s * BM * 32);
    dma32<BN, NT>(Wb, n0, K, k0 + s * 32, t, Bs + s * BN * 32);
  }
  s_wait_vm<2 * LT>();
  __builtin_amdgcn_s_barrier();
  int pb = 0;
  for (int tt = 0; tt < nt; ++tt) {
    const u16* Asb = As + pb * BM * 32;
    const u16* Bsb = Bs + pb * BN * 32;
    const int p3 = (pb + 3) & 3;
    const bool st = (tt + 3 < nt);     // wave-uniform
    // ======== phase A: frag reads FIRST, then stage-issue ========
    bf16x8 a0 = *lds_frag(Asb, wm + 0 * 16 + fr, fq);
    bf16x8 a1 = *lds_frag(Asb, wm + 1 * 16 + fr, fq);
    bf16x8 b0 = *lds_frag(Bsb, wn + 0 * 16 + fr, fq);
    bf16x8 b1 = *lds_frag(Bsb, wn + 1 * 16 + fr, fq);
    bf16x8 b2 = *lds_frag(Bsb, wn + 2 * 16 + fr, fq);
    bf16x8 b3 = *lds_frag(Bsb, wn + 3 * 16 + fr, fq);
    if (st) dma32<BM, NT>(A, m0, K, k0 + (tt + 3) * 32, t, As + p3 * BM * 32);
    __builtin_amdgcn_sched_barrier(0);
    __builtin_amdgcn_s_barrier();
    asm volatile("s_waitcnt lgkmcnt(0)" ::: "memory");
    __builtin_amdgcn_sched_barrier(0);
    __builtin_amdgcn_s_setprio(1);
    acc[0][0] = MFMA_BF16(a0, b0, acc[0][0], 0, 0, 0);
    acc[0][1] = MFMA_BF16(a0, b1, acc[0][1], 0, 0, 0);
    acc[0][2] = MFMA_BF16(a0, b2, acc[0][2], 0, 0, 0);
    acc[0][3] = MFMA_BF16(a0, b3, acc[0][3], 0, 0, 0);
    acc[1][0] = MFMA_BF16(a1, b0, acc[1][0], 0, 0, 0);
    acc[1][1] = MFMA_BF16(a1, b1, acc[1][1], 0, 0, 0);
    acc[1][2] = MFMA_BF16(a1, b2, acc[1][2], 0, 0, 0);
    acc[1][3] = MFMA_BF16(a1, b3, acc[1][3], 0, 0, 0);
    __builtin_amdgcn_s_setprio(0);
    __builtin_amdgcn_sched_barrier(0);
    __builtin_amdgcn_s_barrier();
    // ======== phase B ========
    bf16x8 a2 = *lds_frag(Asb, wm + 2 * 16 + fr, fq);
    bf16x8 a3 = *lds_frag(Asb, wm + 3 * 16 + fr, fq);
    if (st) dma32<BN, NT>(Wb, n0, K, k0 + (tt + 3) * 32, t, Bs + p3 * BN * 32);
    __builtin_amdgcn_sched_barrier(0);
    __builtin_amdgcn_s_barrier();
    asm volatile("s_waitcnt lgkmcnt(0)" ::: "memory");
    __builtin_amdgcn_sched_barrier(0);
    __builtin_amdgcn_s_setprio(1);
    acc[2][0] = MFMA_BF16(a2, b0, acc[2][0], 0, 0, 0);
    acc[2][1] = MFMA_BF16(a2, b1, acc[2][1], 0, 0, 0);
    acc[2][2] = MFMA_BF16(a2, b2, acc[2][2], 0, 0, 0);
    acc[2][3] = MFMA_BF16(a2, b3, acc[2][3], 0, 0, 0);
    acc[3][0] = MFMA_BF16(a3, b0, acc[3][0], 0, 0, 0);
    acc[3][1] = MFMA_BF16(a3, b1, acc[3][1], 0, 0, 0);
    acc[3][2] = MFMA_BF16(a3, b2, acc[3][2], 0, 0, 0);
    acc[3][3] = MFMA_BF16(a3, b3, acc[3][3], 0, 0, 0);
    __builtin_amdgcn_s_setprio(0);
    __builtin_amdgcn_sched_barrier(0);
    // ======== tile boundary: retire stage(tt+1); barrier = all-waves landed ====
    if (tt + 1 < nt) {
      const int rem = nt - 2 - tt;     // stages still wanted in flight
      if (rem >= 2)      s_wait_vm<2 * LT>();
      else if (rem == 1) s_wait_vm<LT>();
      else               s_wait_vm<0>();
      __builtin_amdgcn_s_barrier();
    }
    pb = (pb + 1) & 3;
  }
}

// ---------------- MFMA GEMM: C[M,N](bf16) = A(bf16) @ Wb(bf16,[N,K])^T ----------------
// 256x128 tile, 8 waves (4M x 2N, per-wave 64x64), phased pipeline.
template<int BM, int BN, int ACT>
__global__ __launch_bounds__((BM/64)*(BN/64)*64)
void mfma_gemm(const u16* __restrict__ A, const u16* __restrict__ Wb,
               u16* __restrict__ Cb, int N, int K) {
  constexpr int WCOLS = BN / 64;
  __shared__ u16 As[4 * BM * 32];
  __shared__ u16 Bs[4 * BN * 32];
  int bx, by, bz;
  xcd_remap(bx, by, bz);
  const int t = threadIdx.x;
  const int lane = t & 63, w = t >> 6;
  const int wm = (w / WCOLS) * 64, wn = (w % WCOLS) * 64;
  const int m0 = by * BM, n0 = bx * BN;
  const int fr = lane & 15, fq = lane >> 4;

  f32x4 acc[4][4] = {};
  gemm_pipe<BM, BN>(A, Wb, K, 0, K / 32, m0, n0, As, Bs, t, wm, wn, fr, fq, acc);

  #pragma unroll
  for (int i = 0; i < 4; i++)
    #pragma unroll
    for (int j = 0; j < 4; j++)
      #pragma unroll
      for (int r = 0; r < 4; r++) {
        const int row = m0 + wm + i * 16 + fq * 4 + r;
        const int col = n0 + wn + j * 16 + fr;
        float val = acc[i][j][r];
        if (ACT == 1) val = gelu_exact(val);
        Cb[(size_t)row * N + col] = f2b(val);
      }
}

// ---- f32-out MFMA GEMM, NO ATOMICS (replaces split-K atomic path) ----
// z==0: Co[row,col] = resid[row,col] (+bias[col]) + acc   (covers K-slice 0)
// z==1: P[row,col]  = acc                                  (K-slice 1; P in 2 halves)
// For full-K usage launch gridDim.z == 1 (all z==0 path).
template<int BM, int BN>
__global__ __launch_bounds__((BM/64)*(BN/64)*64)
void mfma_gemm_fo(const u16* __restrict__ A, const u16* __restrict__ Wb,
                  const float* __restrict__ resid, const float* __restrict__ bias,
                  float* __restrict__ Co, float* __restrict__ P0, float* __restrict__ P1,
                  int N, int K, int Kc) {
  constexpr int WCOLS = BN / 64;
  __shared__ u16 As[4 * BM * 32];
  __shared__ u16 Bs[4 * BN * 32];
  int bx, by, bz;
  xcd_remap(bx, by, bz);
  const int t = threadIdx.x;
  const int lane = t & 63, w = t >> 6;
  const int wm = (w / WCOLS) * 64, wn = (w % WCOLS) * 64;
  const int m0 = by * BM, n0 = bx * BN;
  const int fr = lane & 15, fq = lane >> 4;
  const int k0 = bz * Kc;

  f32x4 acc[4][4] = {};
  gemm_pipe<BM, BN>(A, Wb, K, k0, Kc / 32, m0, n0, As, Bs, t, wm, wn, fr, fq, acc);

  if (bz == 0) {
    #pragma unroll
    for (int j = 0; j < 4; j++) {
      const int col = n0 + wn + j * 16 + fr;
      const float bj = (bias != nullptr) ? bias[col] : 0.0f;
      #pragma unroll
      for (int i = 0; i < 4; i++)
        #pragma unroll
        for (int r = 0; r < 4; r++) {
          const int row = m0 + wm + i * 16 + fq * 4 + r;
          const size_t idx = (size_t)row * N + col;
          Co[idx] = resid[idx] + bj + acc[i][j][r];
        }
    }
  } else {
    #pragma unroll
    for (int j = 0; j < 4; j++) {
      const int col = n0 + wn + j * 16 + fr;
      #pragma unroll
      for (int i = 0; i < 4; i++)
        #pragma unroll
        for (int r = 0; r < 4; r++) {
          const int row = m0 + wm + i * 16 + fq * 4 + r;
          float* P = (row < MM / 2) ? P0 : P1;
          P[(size_t)(row & (MM / 2 - 1)) * N + col] = acc[i][j][r];
        }
    }
  }
}

// ---------------- K/V transpose via LDS, coalesced both sides ----------------
__global__ __launch_bounds__(256) void kv_trans(const u16* __restrict__ QKV,
                                                u16* __restrict__ Kt, u16* __restrict__ Vt) {
  __shared__ u16 T[64][72];
  const int tile = blockIdx.x;
  const int h2 = blockIdx.y;             // h = h2&15, which = h2>>4 (0=K, 1=V)
  const int b = blockIdx.z;
  const int h = h2 & 15, which = h2 >> 4;
  const int t = threadIdx.x;
  const int pos = t >> 2, d0 = (t & 3) * 16;
  const u16* src = QKV + ((size_t)(b * LL) + tile * 64 + pos) * QS + 1024 + which * 1024 + h * HD + d0;
  union { uint4 u[2]; u16 s[16]; } pk;
  pk.u[0] = reinterpret_cast<const uint4*>(src)[0];
  pk.u[1] = reinterpret_cast<const uint4*>(src)[1];
  #pragma unroll
  for (int j = 0; j < 16; j++) T[d0 + j][pos] = pk.s[j];
  __syncthreads();
  const int d = t >> 2, p0 = (t & 3) * 16;
  u16* dst = (which ? Vt : Kt) + ((size_t)(b * HH + h) * HD + d) * LL + tile * 64 + p0;
  union { uint4 u[2]; u16 s[16]; } ok;
  #pragma unroll
  for (int j = 0; j < 16; j++) ok.s[j] = T[d][p0 + j];
  reinterpret_cast<uint4*>(dst)[0] = ok.u[0];
  reinterpret_cast<uint4*>(dst)[1] = ok.u[1];
}

// ---------------- attention phase 1 ----------------
__global__ __launch_bounds__(256) void attn_phase1(const u16* __restrict__ QKV,
                                                   const u16* __restrict__ Kt,
                                                   const u16* __restrict__ Vt,
                                                   u16* __restrict__ Oa,
                                                   u16* __restrict__ Slt) {
  __shared__ u16 Ss[4][16][64];
  const int tile = blockIdx.x, h = blockIdx.y, b = blockIdx.z;
  const int t = threadIdx.x, lane = t & 63, w = t >> 6;
  const int fr = lane & 15, fq = lane >> 4;
  const size_t tok0 = (size_t)(b * LL + tile * 64);
  const size_t bh = (size_t)(b * HH + h);
  const u16* Qb  = QKV + tok0 * QS + h * HD;
  const u16* Kb  = Qb + 1024;
  const u16* Ktb = Kt + bh * (HD * LL) + tile * 64;
  const u16* Vtb = Vt + bh * (HD * LL) + tile * 64;

  // ---- S = Q K^T ----
  bf16x8 aq[2], bk[4][2];
  #pragma unroll
  for (int kh = 0; kh < 2; kh++)
    aq[kh] = *reinterpret_cast<const bf16x8*>(Qb + (size_t)(16*w + fr) * QS + kh*32 + fq*8);
  #pragma unroll
  for (int n4 = 0; n4 < 4; n4++)
    #pragma unroll
    for (int kh = 0; kh < 2; kh++)
      bk[n4][kh] = *reinterpret_cast<const bf16x8*>(Kb + (size_t)(16*n4 + fr) * QS + kh*32 + fq*8);
  f32x4 sacc[4] = {};
  #pragma unroll
  for (int n4 = 0; n4 < 4; n4++) {
    sacc[n4] = MFMA_BF16(aq[0], bk[n4][0], sacc[n4], 0, 0, 0);
    sacc[n4] = MFMA_BF16(aq[1], bk[n4][1], sacc[n4], 0, 0, 0);
  }
  #pragma unroll
  for (int n4 = 0; n4 < 4; n4++)
    #pragma unroll
    for (int r = 0; r < 4; r++) {
      const bool keep = (16*w + 4*fq + r) >= (16*n4 + fr);
      Ss[w][4*fq + r][16*n4 + fr] = keep ? f2b(sacc[n4][r]) : (u16)0;
    }
  __syncthreads();

  // ---- Slt = V^T K ----
  bf16x8 va[2], kt[4][2];
  #pragma unroll
  for (int kh = 0; kh < 2; kh++)
    va[kh] = *reinterpret_cast<const bf16x8*>(Vtb + (size_t)(16*w + fr) * LL + kh*32 + fq*8);
  #pragma unroll
  for (int n4 = 0; n4 < 4; n4++)
    #pragma unroll
    for (int kh = 0; kh < 2; kh++)
      kt[n4][kh] = *reinterpret_cast<const bf16x8*>(Ktb + (size_t)(16*n4 + fr) * LL + kh*32 + fq*8);
  f32x4 lacc[4] = {};
  #pragma unroll
  for (int n4 = 0; n4 < 4; n4++) {
    lacc[n4] = MFMA_BF16(va[0], kt[n4][0], lacc[n4], 0, 0, 0);
    lacc[n4] = MFMA_BF16(va[1], kt[n4][1], lacc[n4], 0, 0, 0);
  }
  u16* So = Slt + (bh * 16 + tile) * 4096;
  #pragma unroll
  for (int n4 = 0; n4 < 4; n4++)
    #pragma unroll
    for (int r = 0; r < 4; r++)
      So[(size_t)(16*w + 4*fq + r) * 64 + 16*n4 + fr] = f2b(lacc[n4][r]);

  // ---- O_intra = S V ----
  bf16x8 sa[2], vb[4][2];
  #pragma unroll
  for (int kh = 0; kh < 2; kh++)
    sa[kh] = *reinterpret_cast<const bf16x8*>(&Ss[w][fr][kh*32 + fq*8]);
  #pragma unroll
  for (int n4 = 0; n4 < 4; n4++)
    #pragma unroll
    for (int kh = 0; kh < 2; kh++)
      vb[n4][kh] = *reinterpret_cast<const bf16x8*>(Vtb + (size_t)(16*n4 + fr) * LL + kh*32 + fq*8);
  f32x4 oacc[4] = {};
  #pragma unroll
  for (int n4 = 0; n4 < 4; n4++) {
    oacc[n4] = MFMA_BF16(sa[0], vb[n4][0], oacc[n4], 0, 0, 0);
    oacc[n4] = MFMA_BF16(sa[1], vb[n4][1], oacc[n4], 0, 0, 0);
  }
  u16* Ob = Oa + (tok0 + 16*w) * DD + h * HD;
  #pragma unroll
  for (int n4 = 0; n4 < 4; n4++)
    #pragma unroll
    for (int r = 0; r < 4; r++)
      Ob[(size_t)(4*fq + r) * DD + 16*n4 + fr] = f2b(oacc[n4][r]);
}

// ---------------- attention phase 2: exclusive fp32 scan ----------------
__global__ __launch_bounds__(256) void attn_phase2(const u16* __restrict__ Slt,
                                                   u16* __restrict__ Wc) {
  const int rg = blockIdx.x, h = blockIdx.y, b = blockIdx.z;
  const size_t base = ((size_t)((b * HH + h) * 16)) * 4096 + rg * 512 + threadIdx.x * 2;
  float r0 = 0.f, r1 = 0.f;
  for (int tl = 0; tl < 16; tl++) {
    const size_t p = base + (size_t)tl * 4096;
    const unsigned d = *reinterpret_cast<const unsigned*>(Slt + p);
    *reinterpret_cast<unsigned*>(Wc + p) = (unsigned)f2b(r0) | ((unsigned)f2b(r1) << 16);
    r0 += b2f((u16)(d & 0xffff));
    r1 += b2f((u16)(d >> 16));
  }
}

// ---------------- attention phase 3: O += Q @ W_prev ----------------
__global__ __launch_bounds__(256) void attn_phase3(const u16* __restrict__ QKV,
                                                   const u16* __restrict__ Wc,
                                                   u16* __restrict__ Oa) {
  const int tile = blockIdx.x, h = blockIdx.y, b = blockIdx.z;
  const int t = threadIdx.x, lane = t & 63, w = t >> 6;
  const int fr = lane & 15, fq = lane >> 4;
  const size_t tok0 = (size_t)(b * LL + tile * 64);
  const size_t bh = (size_t)(b * HH + h);
  const u16* Qb = QKV + tok0 * QS + h * HD;
  const u16* Wb = Wc + (bh * 16 + tile) * 4096;

  bf16x8 aq[2], wb[4][2];
  #pragma unroll
  for (int kh = 0; kh < 2; kh++)
    aq[kh] = *reinterpret_cast<const bf16x8*>(Qb + (size_t)(16*w + fr) * QS + kh*32 + fq*8);
  #pragma unroll
  for (int n4 = 0; n4 < 4; n4++)
    #pragma unroll
    for (int kh = 0; kh < 2; kh++)
      wb[n4][kh] = *reinterpret_cast<const bf16x8*>(Wb + (size_t)(16*n4 + fr) * 64 + kh*32 + fq*8);
  f32x4 oacc[4] = {};
  #pragma unroll
  for (int n4 = 0; n4 < 4; n4++) {
    oacc[n4] = MFMA_BF16(aq[0], wb[n4][0], oacc[n4], 0, 0, 0);
    oacc[n4] = MFMA_BF16(aq[1], wb[n4][1], oacc[n4], 0, 0, 0);
  }
  u16* Ob = Oa + (tok0 + 16*w) * DD + h * HD;
  #pragma unroll
  for (int n4 = 0; n4 < 4; n4++)
    #pragma unroll
    for (int r = 0; r < 4; r++) {
      const size_t idx = (size_t)(4*fq + r) * DD + 16*n4 + fr;
      Ob[idx] = f2b(b2f(Ob[idx]) + oacc[n4][r]);
    }
}

// ---------------- host ----------------
// ws map (32 MB): wbuf 0..8 (time-shared with Slt 0..4 / Wcum 4..8 during attn)
// h/a/m 8..12 (P0 during FC2) | qkv 12..24 | f 12..28 (qkv/Vt dead) | Vt 24..28 |
// Kt 28..32 (P1 during FC2). fp32 residual stream lives in d_out.
extern "C" void kernel_launch(void* const* d_in, const int* in_sizes, int n_in,
                              void* d_out, int out_size, void* d_ws, size_t ws_size,
                              hipStream_t stream) {
  const float* x_in = (const float*)d_in[0];
  const float* qw   = (const float*)d_in[1];
  const float* kw   = (const float*)d_in[2];
  const float* vw   = (const float*)d_in[3];
  const float* ow   = (const float*)d_in[4];
  const float* pn   = (const float*)d_in[5];
  const float* ln   = (const float*)d_in[6];
  const float* fcw  = (const float*)d_in[7];
  const float* fc2w = (const float*)d_in[8];
  const float* fc2b = (const float*)d_in[9];

  char* ws = (char*)d_ws;
  u16* wbuf = (u16*)ws;
  u16* slt  = (u16*)ws;
  u16* wcum = (u16*)(ws + (size_t)(4 << 20));
  u16* h    = (u16*)(ws + (size_t)(8 << 20));
  u16* qkv  = (u16*)(ws + (size_t)(12 << 20));
  u16* f    = (u16*)(ws + (size_t)(12 << 20));
  u16* vt   = (u16*)(ws + (size_t)(24 << 20));
  u16* kt   = (u16*)(ws + (size_t)(28 << 20));
  float* p0 = (float*)(ws + (size_t)(8 << 20));   // FC2 partial, rows 0..1023 (h dead)
  float* p1 = (float*)(ws + (size_t)(28 << 20));  // FC2 partial, rows 1024..2047 (kt dead)
  float* xf = (float*)d_out;

  const int n8D = DD * DD / 8;
  const int n8F = DFFN * DD / 8;

  for (int i = 0; i < 2; i++) {
    const float* qwi  = qw   + (size_t)i * DD * DD;
    const float* kwi  = kw   + (size_t)i * DD * DD;
    const float* vwi  = vw   + (size_t)i * DD * DD;
    const float* owi  = ow   + (size_t)i * DD * DD;
    const float* fcwi = fcw  + (size_t)i * DFFN * DD;
    const float* f2wi = fc2w + (size_t)i * DD * DFFN;
    const float* src  = (i == 0) ? x_in : xf;

    rmsnorm_kernel<<<MM, 256, 0, stream>>>(src, pn + i * DD, h);
    // fused QKV projection: 256x128 tiles -> 192 blocks, phased pipeline
    castw3_kernel<<<dim3(n8D / 256, 3), 256, 0, stream>>>(qwi, kwi, vwi, wbuf, n8D);
    mfma_gemm<256, 128, 0><<<dim3(QS / 128, MM / 256), 512, 0, stream>>>(
        h, wbuf, qkv, QS, DD);
    // chunked linear attention (a = h region)
    kv_trans<<<dim3(16, 32, BB), 256, 0, stream>>>(qkv, kt, vt);
    attn_phase1<<<dim3(16, HH, BB), 256, 0, stream>>>(qkv, kt, vt, h, slt);
    attn_phase2<<<dim3(8, HH, BB), 256, 0, stream>>>(slt, wcum);
    attn_phase3<<<dim3(16, HH, BB), 256, 0, stream>>>(qkv, wcum, h);
    // O-proj: xf = src + a @ ow^T  -- full K, NO atomics, fused residual
    castw_kernel<<<n8D / 256, 256, 0, stream>>>(owi, wbuf, n8D);
    mfma_gemm_fo<128, 64><<<dim3(DD / 64, MM / 128, 1), 128, 0, stream>>>(
        h, wbuf, src, nullptr, xf, p0, p1, DD, DD, DD);
    // MLP
    rmsnorm_kernel<<<MM, 256, 0, stream>>>(xf, ln + i * DD, h);
    castw_kernel<<<n8F / 256, 256, 0, stream>>>(fcwi, wbuf, n8F);
    // FC1: 256x128 tiles -> 256 blocks, phased pipeline
    mfma_gemm<256, 128, 1><<<dim3(DFFN / 128, MM / 256), 512, 0, stream>>>(
        h, wbuf, f, DFFN, DD);
    castw_kernel<<<n8F / 256, 256, 0, stream>>>(f2wi, wbuf, n8F);
    float* co = (i == 1) ? (float*)d_out : xf;
    // FC2: SPLIT=2, NO atomics: z0 -> co = resid+bias+acc, z1 -> partial P; then reduce
    mfma_gemm_fo<128, 64><<<dim3(DD / 64, MM / 128, 2), 128, 0, stream>>>(
        f, wbuf, xf, fc2b + i * DD, co, p0, p1, DD, DFFN, DFFN / 2);
    reduce_add_kernel<<<MM * DD / 4 / 256, 256, 0, stream>>>(co, p0, p1);
  }
}